// Round 20
// baseline (123.676 us; speedup 1.0000x reference)
//
#include <hip/hip_runtime.h>
#include <hip/hip_bf16.h>

#define B_  2
#define T_  2048
#define C_  1024
#define H_  16
#define D_  64
#define M_  (B_*T_)   // 4096
#define N1_ (3*C_)    // 3072

typedef short bf16x8 __attribute__((ext_vector_type(8)));
typedef short bf16x4 __attribute__((ext_vector_type(4)));
typedef float f32x4 __attribute__((ext_vector_type(4)));
typedef unsigned short u16;
typedef u16 u16x8 __attribute__((ext_vector_type(8)));

#define QSCALE 0.18033688011112042f   // (1/8) * log2(e)
#define C8     11.541560327111707f    // 8 * log2(e)

__device__ __forceinline__ u16 f2bf(float f) {
  unsigned u = __float_as_uint(f);
  u += 0x7FFFu + ((u >> 16) & 1u);
  return (u16)(u >> 16);
}

__device__ __forceinline__ void gload16(const void* g, void* l) {
  __builtin_amdgcn_global_load_lds((__attribute__((address_space(1))) void*)g,
                                   (__attribute__((address_space(3))) void*)l,
                                   16, 0, 0);
}

// ---------------- fp32 -> bf16 conversion, 3 sources -> contiguous ws ----------------
__global__ __launch_bounds__(256) void cvt3(const float* __restrict__ x,
                                            const float* __restrict__ wa,
                                            const float* __restrict__ wp,
                                            u16* __restrict__ out) {
  int i = (blockIdx.x * 256 + threadIdx.x) * 8;
  const float* src;
  int off;
  if (i < M_ * C_)                 { src = x;  off = 0; }
  else if (i < M_ * C_ + N1_ * C_) { src = wa; off = M_ * C_; }
  else                             { src = wp; off = M_ * C_ + N1_ * C_; }
  float4 a = *(const float4*)(src + (i - off));
  float4 b = *(const float4*)(src + (i - off) + 4);
  u16x8 o;
  o[0] = f2bf(a.x); o[1] = f2bf(a.y); o[2] = f2bf(a.z); o[3] = f2bf(a.w);
  o[4] = f2bf(b.x); o[5] = f2bf(b.y); o[6] = f2bf(b.z); o[7] = f2bf(b.w);
  *(u16x8*)(out + i) = o;
}

// ---------------- GEMM mainloop, BK=64: C += A[M,K] * W[N,K]^T ----------------
// LDS [128][64] per operand, granule-XOR swizzle (g ^= row&7): staged via
// pre-swizzled global source + linear gload16 dest; frag ds_read_b128 at
// 2-way aliasing (free). 16 K-steps at K=1024 (half the barriers of BK=32).
__device__ __forceinline__ void gemm_core(const u16* __restrict__ A,
                                          const u16* __restrict__ W,
                                          u16* As, u16* Bs,
                                          f32x4 (&acc)[4][4],
                                          int m0, int n0, int K) {
  int tid = threadIdx.x;
  int lane = tid & 63, wid = tid >> 6;
  int wr = wid >> 1, wc = wid & 1;

  int srow = lane >> 3;                 // 0..7
  int sg = (lane & 7) ^ srow;           // pre-swizzled source granule
  const u16* aSrc = A + (size_t)(m0 + wid * 32 + srow) * K + sg * 8;
  const u16* bSrc = W + (size_t)(n0 + wid * 32 + srow) * K + sg * 8;
  u16* aDst = As + (wid * 32) * 64;
  u16* bDst = Bs + (wid * 32) * 64;

  int rg = lane >> 4, cl = lane & 15;
  int arb[4], ar7[4], brb[4], br7[4];
#pragma unroll
  for (int m = 0; m < 4; ++m) {
    int row = wr * 64 + m * 16 + cl;
    arb[m] = row * 64; ar7[m] = row & 7;
    row = wc * 64 + m * 16 + cl;
    brb[m] = row * 64; br7[m] = row & 7;
  }

  for (int kt = 0; kt < K / 64; ++kt) {
    int k0 = kt * 64;
    __syncthreads();
#pragma unroll
    for (int i = 0; i < 4; ++i) {
      gload16(aSrc + (size_t)i * 8 * K + k0, aDst + i * 8 * 64);
      gload16(bSrc + (size_t)i * 8 * K + k0, bDst + i * 8 * 64);
    }
    __syncthreads();

#pragma unroll
    for (int kh = 0; kh < 2; ++kh) {
      bf16x8 af[4], bfr[4];
#pragma unroll
      for (int m = 0; m < 4; ++m)
        af[m] = *(const bf16x8*)(As + arb[m] + (((kh * 4 + rg) ^ ar7[m]) * 8));
#pragma unroll
      for (int n = 0; n < 4; ++n)
        bfr[n] = *(const bf16x8*)(Bs + brb[n] + (((kh * 4 + rg) ^ br7[n]) * 8));
#pragma unroll
      for (int m = 0; m < 4; ++m)
#pragma unroll
        for (int n = 0; n < 4; ++n)
          acc[m][n] = __builtin_amdgcn_mfma_f32_16x16x32_bf16(af[m], bfr[n], acc[m][n], 0, 0, 0);
    }
  }
}

// ---------------- GEMM1: qkv = x @ W_attn^T + b; Q pre-scaled by log2e/8 ----------------
// V segment (n0>=2048) stores via LDS transpose -> 16B coalesced writes.
__global__ __launch_bounds__(256) void gemm_qkv(const u16* __restrict__ A,
                                                const u16* __restrict__ W,
                                                const float* __restrict__ bias,
                                                u16* __restrict__ Qb,
                                                u16* __restrict__ Kb,
                                                u16* __restrict__ Vt) {
  __shared__ __align__(16) u16 Sh[2][128 * 64];   // As/Bs; reused as 32KB transpose
  f32x4 acc[4][4] = {};
  int m0 = blockIdx.x * 128, n0 = blockIdx.y * 128;
  gemm_core(A, W, Sh[0], Sh[1], acc, m0, n0, C_);

  int tid = threadIdx.x;
  int lane = tid & 63, wid = tid >> 6;
  int wr = wid >> 1, wc = wid & 1;
  int rg = lane >> 4, cl = lane & 15;
  int seg = n0 >> 10;                   // whole block in one segment

  if (seg < 2) {
    float sc = (seg == 0) ? QSCALE : 1.0f;
#pragma unroll
    for (int n = 0; n < 4; ++n) {
      int gn = n0 + wc * 64 + n * 16 + cl;
      float bv = bias[gn];
      int cc = gn & 1023;
      int h = cc >> 6, d = cc & 63;
#pragma unroll
      for (int m = 0; m < 4; ++m) {
#pragma unroll
        for (int r = 0; r < 4; ++r) {
          int gm = m0 + wr * 64 + m * 16 + rg * 4 + r;
          int b = gm >> 11, t = gm & 2047;
          u16 val = f2bf((acc[m][n][r] + bv) * sc);
          int bh = b * 16 + h;
          if (seg == 0) Qb[((size_t)(bh * 2048 + t)) * 64 + d] = val;
          else          Kb[((size_t)(bh * 2048 + t)) * 64 + d] = val;
        }
      }
    }
  } else {
    // V: bias+cvt into transpose tile Tr[gn_loc][gm_loc], then coalesced store
    __syncthreads();                    // all waves done reading As/Bs
    u16* Tr = &Sh[0][0];                // [128][128] bf16 = 32KB
#pragma unroll
    for (int n = 0; n < 4; ++n) {
      int gnl = wc * 64 + n * 16 + cl;
      float bv = bias[n0 + gnl];
#pragma unroll
      for (int m = 0; m < 4; ++m)
#pragma unroll
        for (int r = 0; r < 4; ++r)
          Tr[gnl * 128 + wr * 64 + m * 16 + rg * 4 + r] = f2bf(acc[m][n][r] + bv);
    }
    __syncthreads();
    int b = m0 >> 11, t0 = m0 & 2047;
    int ccb = n0 - 2048;
#pragma unroll
    for (int it = 0; it < 8; ++it) {
      int idx = it * 256 + tid;
      int dl = idx >> 4, oct = idx & 15;
      int cc = ccb + dl;
      int bh = b * 16 + (cc >> 6), d = cc & 63;
      *(u16x8*)(Vt + ((size_t)(bh * 64 + d)) * 2048 + t0 + oct * 8) =
          *(const u16x8*)(Tr + dl * 128 + oct * 8);
    }
  }
}

// ---------------- GEMM2: out = y @ W_proj^T + b (fp32 out) ----------------
__global__ __launch_bounds__(256) void gemm_proj(const u16* __restrict__ A,
                                                 const u16* __restrict__ W,
                                                 const float* __restrict__ bias,
                                                 float* __restrict__ out) {
  __shared__ __align__(16) u16 Sh[2][128 * 64];
  f32x4 acc[4][4] = {};
  int m0 = blockIdx.x * 128, n0 = blockIdx.y * 128;
  gemm_core(A, W, Sh[0], Sh[1], acc, m0, n0, C_);

  int lane = threadIdx.x & 63, wid = threadIdx.x >> 6;
  int wr = wid >> 1, wc = wid & 1;
  int rg = lane >> 4, cl = lane & 15;
#pragma unroll
  for (int n = 0; n < 4; ++n) {
    int gn = n0 + wc * 64 + n * 16 + cl;
    float bv = bias[gn];
#pragma unroll
    for (int m = 0; m < 4; ++m) {
#pragma unroll
      for (int r = 0; r < 4; ++r) {
        int gm = m0 + wr * 64 + m * 16 + rg * 4 + r;
        out[(size_t)gm * 1024 + gn] = acc[m][n][r] + bv;
      }
    }
  }
}

// ---------------- flash attention v19: 4-wave shared LDS-staged K/V (unchanged) ------
__global__ __launch_bounds__(256, 2) void attn_fwd(const u16* __restrict__ Qb,
                                                   const u16* __restrict__ Kb,
                                                   const u16* __restrict__ Vt,
                                                   u16* __restrict__ Yb) {
  __shared__ __align__(16) u16 Ks[2][64 * 64];
  __shared__ __align__(16) u16 Vs[2][64 * 64];
  __shared__ __align__(16) u16 Ps[4][32 * 64];
  int tid = threadIdx.x, lane = tid & 63, w = tid >> 6;
  int cl = lane & 15, kg = lane >> 4;
  int bid = blockIdx.x;
  int bh = bid & 31;
  int i = bid >> 5;
  int qt = (i < 8) ? i : 23 - i;
  int qb0 = qt * 128 + w * 32;
  int jmaxw = (qb0 + 31) >> 6;
  int jmaxb = 2 * qt + 1;
  const u16* Qp = Qb + (size_t)bh * (2048 * 64);
  const u16* Kp = Kb + (size_t)bh * (2048 * 64);
  const u16* Vp = Vt + (size_t)bh * (64 * 2048);
  u16* Pw = Ps[w];

  int srow8 = lane >> 3;
  int sg = (lane & 7) ^ srow8;
  const u16* Ksrc = Kp + (w * 16 + srow8) * 64 + sg * 8;
  const u16* Vsrc = Vp + (w * 16 + srow8) * 2048 + sg * 8;

  bf16x8 qf[2][2];
#pragma unroll
  for (int fr = 0; fr < 2; ++fr)
#pragma unroll
    for (int dk = 0; dk < 2; ++dk)
      qf[fr][dk] = *(const bf16x8*)(Qp + (qb0 + fr * 16 + cl) * 64 + dk * 32 + kg * 8);

  f32x4 o[2][4] = {};
  float lsum[2] = {0.f, 0.f};
  const f32x4 CINIT = {-C8, -C8, -C8, -C8};

  auto STAGE = [&](int j, int buf) {
    u16* kd = &Ks[buf][w * 1024];
    u16* vd = &Vs[buf][w * 1024];
    const u16* ks = Ksrc + j * 4096;
    const u16* vs = Vsrc + j * 64;
    gload16(ks, kd);
    gload16(ks + 512, kd + 512);
    gload16(vs, vd);
    gload16(vs + 8 * 2048, vd + 512);
  };

  auto FULL = [&](int buf) {
    const u16* Kl = Ks[buf];
    const u16* Vl = Vs[buf];
    bf16x8 kf[4][2], vf[4][2];
#pragma unroll
    for (int fc = 0; fc < 4; ++fc) {
      int row = fc * 16 + cl;
      kf[fc][0] = *(const bf16x8*)(Kl + row * 64 + ((kg ^ (cl & 7)) * 8));
      kf[fc][1] = *(const bf16x8*)(Kl + row * 64 + (((4 + kg) ^ (cl & 7)) * 8));
    }
#pragma unroll
    for (int dc = 0; dc < 4; ++dc) {
      int row = dc * 16 + cl;
      vf[dc][0] = *(const bf16x8*)(Vl + row * 64 + ((kg ^ (cl & 7)) * 8));
      vf[dc][1] = *(const bf16x8*)(Vl + row * 64 + (((4 + kg) ^ (cl & 7)) * 8));
    }
    f32x4 s[2][4];
#pragma unroll
    for (int fc = 0; fc < 4; ++fc)
#pragma unroll
      for (int fr = 0; fr < 2; ++fr) {
        f32x4 z = CINIT;
        z = __builtin_amdgcn_mfma_f32_16x16x32_bf16(kf[fc][0], qf[fr][0], z, 0, 0, 0);
        z = __builtin_amdgcn_mfma_f32_16x16x32_bf16(kf[fc][1], qf[fr][1], z, 0, 0, 0);
        s[fr][fc] = z;
      }
#pragma unroll
    for (int fr = 0; fr < 2; ++fr) {
      int rowb = (fr * 16 + cl) * 64;
#pragma unroll
      for (int fc = 0; fc < 4; ++fc) {
        float p0 = exp2f(s[fr][fc][0]);
        float p1 = exp2f(s[fr][fc][1]);
        float p2 = exp2f(s[fr][fc][2]);
        float p3 = exp2f(s[fr][fc][3]);
        lsum[fr] += (p0 + p1) + (p2 + p3);
        union { bf16x4 v; __hip_bfloat162 h[2]; } pk;
        pk.h[0] = __float22bfloat162_rn(make_float2(p0, p1));
        pk.h[1] = __float22bfloat162_rn(make_float2(p2, p3));
        *(bf16x4*)(Pw + rowb + (((fc * 2 + (kg >> 1)) ^ (cl & 7)) * 8) + (kg & 1) * 4) = pk.v;
      }
    }
    bf16x8 pf[2][2];
#pragma unroll
    for (int fr = 0; fr < 2; ++fr) {
      int rowb = (fr * 16 + cl) * 64;
      pf[fr][0] = *(const bf16x8*)(Pw + rowb + ((kg ^ (cl & 7)) * 8));
      pf[fr][1] = *(const bf16x8*)(Pw + rowb + (((kg + 4) ^ (cl & 7)) * 8));
    }
#pragma unroll
    for (int kv2 = 0; kv2 < 2; ++kv2)
#pragma unroll
      for (int dc = 0; dc < 4; ++dc) {
        o[0][dc] = __builtin_amdgcn_mfma_f32_16x16x32_bf16(pf[0][kv2], vf[dc][kv2], o[0][dc], 0, 0, 0);
        o[1][dc] = __builtin_amdgcn_mfma_f32_16x16x32_bf16(pf[1][kv2], vf[dc][kv2], o[1][dc], 0, 0, 0);
      }
  };

  auto EDGE = [&](int buf, int j) {
    const u16* Kl = Ks[buf];
    const u16* Vl = Vs[buf];
    int par = w & 1;
    int fcTop = par ? 3 : 1;
    int kvTop = par;
    bf16x8 kf[4][2], vf[4][2];
#pragma unroll
    for (int fc = 0; fc < 4; ++fc)
      if (fc <= fcTop) {
        int row = fc * 16 + cl;
        kf[fc][0] = *(const bf16x8*)(Kl + row * 64 + ((kg ^ (cl & 7)) * 8));
        kf[fc][1] = *(const bf16x8*)(Kl + row * 64 + (((4 + kg) ^ (cl & 7)) * 8));
      }
#pragma unroll
    for (int dc = 0; dc < 4; ++dc) {
      int row = dc * 16 + cl;
      vf[dc][0] = *(const bf16x8*)(Vl + row * 64 + ((kg ^ (cl & 7)) * 8));
      if (kvTop) vf[dc][1] = *(const bf16x8*)(Vl + row * 64 + (((4 + kg) ^ (cl & 7)) * 8));
    }
    f32x4 s[2][4];
#pragma unroll
    for (int fc = 0; fc < 4; ++fc)
      if (fc <= fcTop) {
#pragma unroll
        for (int fr = 0; fr < 2; ++fr) {
          f32x4 z = CINIT;
          z = __builtin_amdgcn_mfma_f32_16x16x32_bf16(kf[fc][0], qf[fr][0], z, 0, 0, 0);
          z = __builtin_amdgcn_mfma_f32_16x16x32_bf16(kf[fc][1], qf[fr][1], z, 0, 0, 0);
          s[fr][fc] = z;
        }
      }
#pragma unroll
    for (int fr = 0; fr < 2; ++fr) {
      int rowb = (fr * 16 + cl) * 64;
      int qg = qb0 + fr * 16 + cl;
#pragma unroll
      for (int fc = 0; fc < 4; ++fc) {
        bf16x4 pw;
        if (fc <= fcTop) {
#pragma unroll
          for (int r = 0; r < 4; ++r) {
            int kvg = j * 64 + fc * 16 + kg * 4 + r;
            float p = (kvg <= qg) ? exp2f(s[fr][fc][r]) : 0.f;
            lsum[fr] += p;
            pw[r] = (short)f2bf(p);
          }
        } else {
          pw[0] = 0; pw[1] = 0; pw[2] = 0; pw[3] = 0;
        }
        *(bf16x4*)(Pw + rowb + (((fc * 2 + (kg >> 1)) ^ (cl & 7)) * 8) + (kg & 1) * 4) = pw;
      }
    }
    bf16x8 pf[2][2];
#pragma unroll
    for (int fr = 0; fr < 2; ++fr) {
      int rowb = (fr * 16 + cl) * 64;
      pf[fr][0] = *(const bf16x8*)(Pw + rowb + ((kg ^ (cl & 7)) * 8));
      if (kvTop) pf[fr][1] = *(const bf16x8*)(Pw + rowb + (((kg + 4) ^ (cl & 7)) * 8));
    }
#pragma unroll
    for (int kv2 = 0; kv2 < 2; ++kv2)
      if (kv2 <= kvTop) {
#pragma unroll
        for (int dc = 0; dc < 4; ++dc) {
          o[0][dc] = __builtin_amdgcn_mfma_f32_16x16x32_bf16(pf[0][kv2], vf[dc][kv2], o[0][dc], 0, 0, 0);
          o[1][dc] = __builtin_amdgcn_mfma_f32_16x16x32_bf16(pf[1][kv2], vf[dc][kv2], o[1][dc], 0, 0, 0);
        }
      }
  };

  STAGE(0, 0);
  __syncthreads();
  int buf = 0;
  for (int j = 0; j <= jmaxb; ++j) {
    if (j < jmaxb) STAGE(j + 1, buf ^ 1);
    if (j < jmaxw)       FULL(buf);
    else if (j == jmaxw) EDGE(buf, j);
    __syncthreads();
    buf ^= 1;
  }

  int b = bh >> 4, h = bh & 15;
#pragma unroll
  for (int fr = 0; fr < 2; ++fr) {
    float l = lsum[fr];
    l += __shfl_xor(l, 16);
    l += __shfl_xor(l, 32);
    float linv = 1.f / l;
    float li[4];
#pragma unroll
    for (int r = 0; r < 4; ++r) li[r] = __shfl(linv, kg * 4 + r);
#pragma unroll
    for (int dc = 0; dc < 4; ++dc)
#pragma unroll
      for (int r = 0; r < 4; ++r) {
        int t = qb0 + fr * 16 + kg * 4 + r;
        int d = dc * 16 + cl;
        Yb[((size_t)(b * 2048 + t)) * 1024 + h * 64 + d] = f2bf(o[fr][dc][r] * li[r]);
      }
  }
}

extern "C" void kernel_launch(void* const* d_in, const int* in_sizes, int n_in,
                              void* d_out, int out_size, void* d_ws, size_t ws_size,
                              hipStream_t stream) {
  const float* x  = (const float*)d_in[0];
  const float* Wa = (const float*)d_in[1];
  const float* ba = (const float*)d_in[2];
  const float* Wp = (const float*)d_in[3];
  const float* bp = (const float*)d_in[4];
  float* out = (float*)d_out;

  u16* xb  = (u16*)d_ws;
  u16* Wab = xb  + (size_t)M_ * C_;
  u16* Wpb = Wab + (size_t)N1_ * C_;
  u16* Qb  = Wpb + (size_t)C_ * C_;
  u16* Kb  = Qb  + (size_t)M_ * C_;
  u16* Vt  = Kb  + (size_t)M_ * C_;
  u16* Yb  = Vt  + (size_t)M_ * C_;

  cvt3<<<(M_ * C_ + N1_ * C_ + C_ * C_) / 2048, 256, 0, stream>>>(x, Wa, Wp, xb);
  gemm_qkv<<<dim3(M_ / 128, N1_ / 128), 256, 0, stream>>>(xb, Wab, ba, Qb, Kb, Vt);
  attn_fwd<<<512, 256, 0, stream>>>(Qb, Kb, Vt, Yb);
  gemm_proj<<<dim3(M_ / 128, C_ / 128), 256, 0, stream>>>(Yb, Wpb, bp, out);
}

// Round 21
// 123.419 us; speedup vs baseline: 1.0021x; 1.0021x over previous
//
#include <hip/hip_runtime.h>
#include <hip/hip_bf16.h>

#define B_  2
#define T_  2048
#define C_  1024
#define H_  16
#define D_  64
#define M_  (B_*T_)   // 4096
#define N1_ (3*C_)    // 3072

typedef short bf16x8 __attribute__((ext_vector_type(8)));
typedef short bf16x4 __attribute__((ext_vector_type(4)));
typedef float f32x4 __attribute__((ext_vector_type(4)));
typedef unsigned short u16;
typedef u16 u16x8 __attribute__((ext_vector_type(8)));

#define QSCALE 0.18033688011112042f   // (1/8) * log2(e)
#define C8     11.541560327111707f    // 8 * log2(e)

__device__ __forceinline__ u16 f2bf(float f) {
  unsigned u = __float_as_uint(f);
  u += 0x7FFFu + ((u >> 16) & 1u);
  return (u16)(u >> 16);
}

__device__ __forceinline__ void gload16(const void* g, void* l) {
  __builtin_amdgcn_global_load_lds((__attribute__((address_space(1))) void*)g,
                                   (__attribute__((address_space(3))) void*)l,
                                   16, 0, 0);
}

// ---------------- fp32 -> bf16 conversion, 3 sources -> contiguous ws ----------------
__global__ __launch_bounds__(256) void cvt3(const float* __restrict__ x,
                                            const float* __restrict__ wa,
                                            const float* __restrict__ wp,
                                            u16* __restrict__ out) {
  int i = (blockIdx.x * 256 + threadIdx.x) * 8;
  const float* src;
  int off;
  if (i < M_ * C_)                 { src = x;  off = 0; }
  else if (i < M_ * C_ + N1_ * C_) { src = wa; off = M_ * C_; }
  else                             { src = wp; off = M_ * C_ + N1_ * C_; }
  float4 a = *(const float4*)(src + (i - off));
  float4 b = *(const float4*)(src + (i - off) + 4);
  u16x8 o;
  o[0] = f2bf(a.x); o[1] = f2bf(a.y); o[2] = f2bf(a.z); o[3] = f2bf(a.w);
  o[4] = f2bf(b.x); o[5] = f2bf(b.y); o[6] = f2bf(b.z); o[7] = f2bf(b.w);
  *(u16x8*)(out + i) = o;
}

// ---------------- GEMM mainloop, BK=32 (R19 proven): C += A[M,K] * W[N,K]^T ----------
__device__ __forceinline__ void gemm_core(const u16* __restrict__ A,
                                          const u16* __restrict__ W,
                                          u16* As, u16* Bs,
                                          f32x4 (&acc)[4][4],
                                          int m0, int n0, int K) {
  int tid = threadIdx.x;
  int lane = tid & 63, wid = tid >> 6;
  int wr = wid >> 1, wc = wid & 1;

  int arow = wid * 16 + (lane >> 2);
  int ag = lane & 3;
  int sg = ag ^ ((arow >> 1) & 3);
  const u16* aSrc0 = A + (size_t)(m0 + arow) * K + sg * 8;
  const u16* aSrc1 = aSrc0 + (size_t)64 * K;
  const u16* bSrc0 = W + (size_t)(n0 + arow) * K + sg * 8;
  const u16* bSrc1 = bSrc0 + (size_t)64 * K;
  u16* aDst0 = As + (wid * 16) * 32;
  u16* aDst1 = As + (64 + wid * 16) * 32;
  u16* bDst0 = Bs + (wid * 16) * 32;
  u16* bDst1 = Bs + (64 + wid * 16) * 32;

  int rg = lane >> 4;
  int aoff[4], boff[4];
#pragma unroll
  for (int m = 0; m < 4; ++m) {
    int row = wr * 64 + m * 16 + (lane & 15);
    aoff[m] = row * 32 + (rg ^ ((row >> 1) & 3)) * 8;
    row = wc * 64 + m * 16 + (lane & 15);
    boff[m] = row * 32 + (rg ^ ((row >> 1) & 3)) * 8;
  }

  for (int kt = 0; kt < K / 32; ++kt) {
    int k0 = kt * 32;
    __syncthreads();
    gload16(aSrc0 + k0, aDst0);
    gload16(aSrc1 + k0, aDst1);
    gload16(bSrc0 + k0, bDst0);
    gload16(bSrc1 + k0, bDst1);
    __syncthreads();

    bf16x8 af[4], bfr[4];
#pragma unroll
    for (int m = 0; m < 4; ++m) af[m] = *(const bf16x8*)(As + aoff[m]);
#pragma unroll
    for (int n = 0; n < 4; ++n) bfr[n] = *(const bf16x8*)(Bs + boff[n]);
#pragma unroll
    for (int m = 0; m < 4; ++m)
#pragma unroll
      for (int n = 0; n < 4; ++n)
        acc[m][n] = __builtin_amdgcn_mfma_f32_16x16x32_bf16(af[m], bfr[n], acc[m][n], 0, 0, 0);
  }
}

// ---------------- GEMM1: qkv = x @ W_attn^T + b; Q pre-scaled by log2e/8 ----------------
// V segment (seg==2) stores via dedicated swizzled LDS transpose tile ->
// 16B coalesced global writes (WRITE_SIZE halved, R20-verified), zero
// occupancy cost (48KB x 3 blocks/CU = 144KB <= 160).
__global__ __launch_bounds__(256) void gemm_qkv(const u16* __restrict__ A,
                                                const u16* __restrict__ W,
                                                const float* __restrict__ bias,
                                                u16* __restrict__ Qb,
                                                u16* __restrict__ Kb,
                                                u16* __restrict__ Vt) {
  __shared__ __align__(16) u16 As[128 * 32];
  __shared__ __align__(16) u16 Bs[128 * 32];
  __shared__ __align__(16) u16 Tr[128 * 128];   // V transpose tile (32KB)
  f32x4 acc[4][4] = {};
  int m0 = blockIdx.x * 128, n0 = blockIdx.y * 128;
  gemm_core(A, W, As, Bs, acc, m0, n0, C_);

  int tid = threadIdx.x;
  int lane = tid & 63, wid = tid >> 6;
  int wr = wid >> 1, wc = wid & 1;
  int rg = lane >> 4, cl = lane & 15;
  int seg = n0 >> 10;

  if (seg < 2) {
    float sc = (seg == 0) ? QSCALE : 1.0f;
#pragma unroll
    for (int n = 0; n < 4; ++n) {
      int gn = n0 + wc * 64 + n * 16 + cl;
      float bv = bias[gn];
      int cc = gn & 1023;
      int h = cc >> 6, d = cc & 63;
#pragma unroll
      for (int m = 0; m < 4; ++m) {
#pragma unroll
        for (int r = 0; r < 4; ++r) {
          int gm = m0 + wr * 64 + m * 16 + rg * 4 + r;
          int b = gm >> 11, t = gm & 2047;
          u16 val = f2bf((acc[m][n][r] + bv) * sc);
          int bh = b * 16 + h;
          if (seg == 0) Qb[((size_t)(bh * 2048 + t)) * 64 + d] = val;
          else          Kb[((size_t)(bh * 2048 + t)) * 64 + d] = val;
        }
      }
    }
  } else {
    // V: bias+cvt into swizzled transpose tile, then coalesced 16B stores
#pragma unroll
    for (int n = 0; n < 4; ++n) {
      int gnl = wc * 64 + n * 16 + cl;
      float bv = bias[n0 + gnl];
      int rb = gnl * 128, sw = gnl & 15;
#pragma unroll
      for (int m = 0; m < 4; ++m)
#pragma unroll
        for (int r = 0; r < 4; ++r) {
          int gml = wr * 64 + m * 16 + rg * 4 + r;
          Tr[rb + (((gml >> 3) ^ sw) << 3) + (gml & 7)] = f2bf(acc[m][n][r] + bv);
        }
    }
    __syncthreads();
    int b = m0 >> 11, t0 = m0 & 2047;
    int ccb = n0 - 2048;
#pragma unroll
    for (int it = 0; it < 8; ++it) {
      int idx = it * 256 + tid;
      int dl = idx >> 4, oct = idx & 15;
      int cc = ccb + dl;
      int bh = b * 16 + (cc >> 6), d = cc & 63;
      *(u16x8*)(Vt + ((size_t)(bh * 64 + d)) * 2048 + t0 + oct * 8) =
          *(const u16x8*)(Tr + dl * 128 + (((oct ^ (dl & 15))) << 3));
    }
  }
}

// ---------------- GEMM2: out = y @ W_proj^T + b (fp32 out) ----------------
__global__ __launch_bounds__(256) void gemm_proj(const u16* __restrict__ A,
                                                 const u16* __restrict__ W,
                                                 const float* __restrict__ bias,
                                                 float* __restrict__ out) {
  __shared__ __align__(16) u16 As[128 * 32];
  __shared__ __align__(16) u16 Bs[128 * 32];
  f32x4 acc[4][4] = {};
  int m0 = blockIdx.x * 128, n0 = blockIdx.y * 128;
  gemm_core(A, W, As, Bs, acc, m0, n0, C_);

  int lane = threadIdx.x & 63, wid = threadIdx.x >> 6;
  int wr = wid >> 1, wc = wid & 1;
  int rg = lane >> 4, cl = lane & 15;
#pragma unroll
  for (int n = 0; n < 4; ++n) {
    int gn = n0 + wc * 64 + n * 16 + cl;
    float bv = bias[gn];
#pragma unroll
    for (int m = 0; m < 4; ++m) {
#pragma unroll
      for (int r = 0; r < 4; ++r) {
        int gm = m0 + wr * 64 + m * 16 + rg * 4 + r;
        out[(size_t)gm * 1024 + gn] = acc[m][n][r] + bv;
      }
    }
  }
}

// ---------------- flash attention v19: 4-wave shared LDS-staged K/V (unchanged) ------
__global__ __launch_bounds__(256, 2) void attn_fwd(const u16* __restrict__ Qb,
                                                   const u16* __restrict__ Kb,
                                                   const u16* __restrict__ Vt,
                                                   u16* __restrict__ Yb) {
  __shared__ __align__(16) u16 Ks[2][64 * 64];
  __shared__ __align__(16) u16 Vs[2][64 * 64];
  __shared__ __align__(16) u16 Ps[4][32 * 64];
  int tid = threadIdx.x, lane = tid & 63, w = tid >> 6;
  int cl = lane & 15, kg = lane >> 4;
  int bid = blockIdx.x;
  int bh = bid & 31;
  int i = bid >> 5;
  int qt = (i < 8) ? i : 23 - i;
  int qb0 = qt * 128 + w * 32;
  int jmaxw = (qb0 + 31) >> 6;
  int jmaxb = 2 * qt + 1;
  const u16* Qp = Qb + (size_t)bh * (2048 * 64);
  const u16* Kp = Kb + (size_t)bh * (2048 * 64);
  const u16* Vp = Vt + (size_t)bh * (64 * 2048);
  u16* Pw = Ps[w];

  int srow8 = lane >> 3;
  int sg = (lane & 7) ^ srow8;
  const u16* Ksrc = Kp + (w * 16 + srow8) * 64 + sg * 8;
  const u16* Vsrc = Vp + (w * 16 + srow8) * 2048 + sg * 8;

  bf16x8 qf[2][2];
#pragma unroll
  for (int fr = 0; fr < 2; ++fr)
#pragma unroll
    for (int dk = 0; dk < 2; ++dk)
      qf[fr][dk] = *(const bf16x8*)(Qp + (qb0 + fr * 16 + cl) * 64 + dk * 32 + kg * 8);

  f32x4 o[2][4] = {};
  float lsum[2] = {0.f, 0.f};
  const f32x4 CINIT = {-C8, -C8, -C8, -C8};

  auto STAGE = [&](int j, int buf) {
    u16* kd = &Ks[buf][w * 1024];
    u16* vd = &Vs[buf][w * 1024];
    const u16* ks = Ksrc + j * 4096;
    const u16* vs = Vsrc + j * 64;
    gload16(ks, kd);
    gload16(ks + 512, kd + 512);
    gload16(vs, vd);
    gload16(vs + 8 * 2048, vd + 512);
  };

  auto FULL = [&](int buf) {
    const u16* Kl = Ks[buf];
    const u16* Vl = Vs[buf];
    bf16x8 kf[4][2], vf[4][2];
#pragma unroll
    for (int fc = 0; fc < 4; ++fc) {
      int row = fc * 16 + cl;
      kf[fc][0] = *(const bf16x8*)(Kl + row * 64 + ((kg ^ (cl & 7)) * 8));
      kf[fc][1] = *(const bf16x8*)(Kl + row * 64 + (((4 + kg) ^ (cl & 7)) * 8));
    }
#pragma unroll
    for (int dc = 0; dc < 4; ++dc) {
      int row = dc * 16 + cl;
      vf[dc][0] = *(const bf16x8*)(Vl + row * 64 + ((kg ^ (cl & 7)) * 8));
      vf[dc][1] = *(const bf16x8*)(Vl + row * 64 + (((4 + kg) ^ (cl & 7)) * 8));
    }
    f32x4 s[2][4];
#pragma unroll
    for (int fc = 0; fc < 4; ++fc)
#pragma unroll
      for (int fr = 0; fr < 2; ++fr) {
        f32x4 z = CINIT;
        z = __builtin_amdgcn_mfma_f32_16x16x32_bf16(kf[fc][0], qf[fr][0], z, 0, 0, 0);
        z = __builtin_amdgcn_mfma_f32_16x16x32_bf16(kf[fc][1], qf[fr][1], z, 0, 0, 0);
        s[fr][fc] = z;
      }
#pragma unroll
    for (int fr = 0; fr < 2; ++fr) {
      int rowb = (fr * 16 + cl) * 64;
#pragma unroll
      for (int fc = 0; fc < 4; ++fc) {
        float p0 = exp2f(s[fr][fc][0]);
        float p1 = exp2f(s[fr][fc][1]);
        float p2 = exp2f(s[fr][fc][2]);
        float p3 = exp2f(s[fr][fc][3]);
        lsum[fr] += (p0 + p1) + (p2 + p3);
        union { bf16x4 v; __hip_bfloat162 h[2]; } pk;
        pk.h[0] = __float22bfloat162_rn(make_float2(p0, p1));
        pk.h[1] = __float22bfloat162_rn(make_float2(p2, p3));
        *(bf16x4*)(Pw + rowb + (((fc * 2 + (kg >> 1)) ^ (cl & 7)) * 8) + (kg & 1) * 4) = pk.v;
      }
    }
    bf16x8 pf[2][2];
#pragma unroll
    for (int fr = 0; fr < 2; ++fr) {
      int rowb = (fr * 16 + cl) * 64;
      pf[fr][0] = *(const bf16x8*)(Pw + rowb + ((kg ^ (cl & 7)) * 8));
      pf[fr][1] = *(const bf16x8*)(Pw + rowb + (((kg + 4) ^ (cl & 7)) * 8));
    }
#pragma unroll
    for (int kv2 = 0; kv2 < 2; ++kv2)
#pragma unroll
      for (int dc = 0; dc < 4; ++dc) {
        o[0][dc] = __builtin_amdgcn_mfma_f32_16x16x32_bf16(pf[0][kv2], vf[dc][kv2], o[0][dc], 0, 0, 0);
        o[1][dc] = __builtin_amdgcn_mfma_f32_16x16x32_bf16(pf[1][kv2], vf[dc][kv2], o[1][dc], 0, 0, 0);
      }
  };

  auto EDGE = [&](int buf, int j) {
    const u16* Kl = Ks[buf];
    const u16* Vl = Vs[buf];
    int par = w & 1;
    int fcTop = par ? 3 : 1;
    int kvTop = par;
    bf16x8 kf[4][2], vf[4][2];
#pragma unroll
    for (int fc = 0; fc < 4; ++fc)
      if (fc <= fcTop) {
        int row = fc * 16 + cl;
        kf[fc][0] = *(const bf16x8*)(Kl + row * 64 + ((kg ^ (cl & 7)) * 8));
        kf[fc][1] = *(const bf16x8*)(Kl + row * 64 + (((4 + kg) ^ (cl & 7)) * 8));
      }
#pragma unroll
    for (int dc = 0; dc < 4; ++dc) {
      int row = dc * 16 + cl;
      vf[dc][0] = *(const bf16x8*)(Vl + row * 64 + ((kg ^ (cl & 7)) * 8));
      if (kvTop) vf[dc][1] = *(const bf16x8*)(Vl + row * 64 + (((4 + kg) ^ (cl & 7)) * 8));
    }
    f32x4 s[2][4];
#pragma unroll
    for (int fc = 0; fc < 4; ++fc)
      if (fc <= fcTop) {
#pragma unroll
        for (int fr = 0; fr < 2; ++fr) {
          f32x4 z = CINIT;
          z = __builtin_amdgcn_mfma_f32_16x16x32_bf16(kf[fc][0], qf[fr][0], z, 0, 0, 0);
          z = __builtin_amdgcn_mfma_f32_16x16x32_bf16(kf[fc][1], qf[fr][1], z, 0, 0, 0);
          s[fr][fc] = z;
        }
      }
#pragma unroll
    for (int fr = 0; fr < 2; ++fr) {
      int rowb = (fr * 16 + cl) * 64;
      int qg = qb0 + fr * 16 + cl;
#pragma unroll
      for (int fc = 0; fc < 4; ++fc) {
        bf16x4 pw;
        if (fc <= fcTop) {
#pragma unroll
          for (int r = 0; r < 4; ++r) {
            int kvg = j * 64 + fc * 16 + kg * 4 + r;
            float p = (kvg <= qg) ? exp2f(s[fr][fc][r]) : 0.f;
            lsum[fr] += p;
            pw[r] = (short)f2bf(p);
          }
        } else {
          pw[0] = 0; pw[1] = 0; pw[2] = 0; pw[3] = 0;
        }
        *(bf16x4*)(Pw + rowb + (((fc * 2 + (kg >> 1)) ^ (cl & 7)) * 8) + (kg & 1) * 4) = pw;
      }
    }
    bf16x8 pf[2][2];
#pragma unroll
    for (int fr = 0; fr < 2; ++fr) {
      int rowb = (fr * 16 + cl) * 64;
      pf[fr][0] = *(const bf16x8*)(Pw + rowb + ((kg ^ (cl & 7)) * 8));
      if (kvTop) pf[fr][1] = *(const bf16x8*)(Pw + rowb + (((kg + 4) ^ (cl & 7)) * 8));
    }
#pragma unroll
    for (int kv2 = 0; kv2 < 2; ++kv2)
      if (kv2 <= kvTop) {
#pragma unroll
        for (int dc = 0; dc < 4; ++dc) {
          o[0][dc] = __builtin_amdgcn_mfma_f32_16x16x32_bf16(pf[0][kv2], vf[dc][kv2], o[0][dc], 0, 0, 0);
          o[1][dc] = __builtin_amdgcn_mfma_f32_16x16x32_bf16(pf[1][kv2], vf[dc][kv2], o[1][dc], 0, 0, 0);
        }
      }
  };

  STAGE(0, 0);
  __syncthreads();
  int buf = 0;
  for (int j = 0; j <= jmaxb; ++j) {
    if (j < jmaxb) STAGE(j + 1, buf ^ 1);
    if (j < jmaxw)       FULL(buf);
    else if (j == jmaxw) EDGE(buf, j);
    __syncthreads();
    buf ^= 1;
  }

  int b = bh >> 4, h = bh & 15;
#pragma unroll
  for (int fr = 0; fr < 2; ++fr) {
    float l = lsum[fr];
    l += __shfl_xor(l, 16);
    l += __shfl_xor(l, 32);
    float linv = 1.f / l;
    float li[4];
#pragma unroll
    for (int r = 0; r < 4; ++r) li[r] = __shfl(linv, kg * 4 + r);
#pragma unroll
    for (int dc = 0; dc < 4; ++dc)
#pragma unroll
      for (int r = 0; r < 4; ++r) {
        int t = qb0 + fr * 16 + kg * 4 + r;
        int d = dc * 16 + cl;
        Yb[((size_t)(b * 2048 + t)) * 1024 + h * 64 + d] = f2bf(o[fr][dc][r] * li[r]);
      }
  }
}

extern "C" void kernel_launch(void* const* d_in, const int* in_sizes, int n_in,
                              void* d_out, int out_size, void* d_ws, size_t ws_size,
                              hipStream_t stream) {
  const float* x  = (const float*)d_in[0];
  const float* Wa = (const float*)d_in[1];
  const float* ba = (const float*)d_in[2];
  const float* Wp = (const float*)d_in[3];
  const float* bp = (const float*)d_in[4];
  float* out = (float*)d_out;

  u16* xb  = (u16*)d_ws;
  u16* Wab = xb  + (size_t)M_ * C_;
  u16* Wpb = Wab + (size_t)N1_ * C_;
  u16* Qb  = Wpb + (size_t)C_ * C_;
  u16* Kb  = Qb  + (size_t)M_ * C_;
  u16* Vt  = Kb  + (size_t)M_ * C_;
  u16* Yb  = Vt  + (size_t)M_ * C_;

  cvt3<<<(M_ * C_ + N1_ * C_ + C_ * C_) / 2048, 256, 0, stream>>>(x, Wa, Wp, xb);
  gemm_qkv<<<dim3(M_ / 128, N1_ / 128), 256, 0, stream>>>(xb, Wab, ba, Qb, Kb, Vt);
  attn_fwd<<<512, 256, 0, stream>>>(Qb, Kb, Vt, Yb);
  gemm_proj<<<dim3(M_ / 128, C_ / 128), 256, 0, stream>>>(Yb, Wpb, bp, out);
}

// Round 22
// 112.642 us; speedup vs baseline: 1.0980x; 1.0957x over previous
//
#include <hip/hip_runtime.h>
#include <hip/hip_bf16.h>

#define B_  2
#define T_  2048
#define C_  1024
#define H_  16
#define D_  64
#define M_  (B_*T_)   // 4096
#define N1_ (3*C_)    // 3072

typedef short bf16x8 __attribute__((ext_vector_type(8)));
typedef short bf16x4 __attribute__((ext_vector_type(4)));
typedef float f32x4 __attribute__((ext_vector_type(4)));
typedef unsigned short u16;
typedef u16 u16x8 __attribute__((ext_vector_type(8)));

#define QSCALE 0.18033688011112042f   // (1/8) * log2(e)
#define C8     11.541560327111707f    // 8 * log2(e)

__device__ __forceinline__ u16 f2bf(float f) {
  unsigned u = __float_as_uint(f);
  u += 0x7FFFu + ((u >> 16) & 1u);
  return (u16)(u >> 16);
}

__device__ __forceinline__ void gload16(const void* g, void* l) {
  __builtin_amdgcn_global_load_lds((__attribute__((address_space(1))) void*)g,
                                   (__attribute__((address_space(3))) void*)l,
                                   16, 0, 0);
}

// ---------------- fp32 -> bf16 conversion, 3 sources -> contiguous ws ----------------
__global__ __launch_bounds__(256) void cvt3(const float* __restrict__ x,
                                            const float* __restrict__ wa,
                                            const float* __restrict__ wp,
                                            u16* __restrict__ out) {
  int i = (blockIdx.x * 256 + threadIdx.x) * 8;
  const float* src;
  int off;
  if (i < M_ * C_)                 { src = x;  off = 0; }
  else if (i < M_ * C_ + N1_ * C_) { src = wa; off = M_ * C_; }
  else                             { src = wp; off = M_ * C_ + N1_ * C_; }
  float4 a = *(const float4*)(src + (i - off));
  float4 b = *(const float4*)(src + (i - off) + 4);
  u16x8 o;
  o[0] = f2bf(a.x); o[1] = f2bf(a.y); o[2] = f2bf(a.z); o[3] = f2bf(a.w);
  o[4] = f2bf(b.x); o[5] = f2bf(b.y); o[6] = f2bf(b.z); o[7] = f2bf(b.w);
  *(u16x8*)(out + i) = o;
}

// ---------------- GEMM mainloop, BK=32 (R19 proven): C += A[M,K] * W[N,K]^T ----------
__device__ __forceinline__ void gemm_core(const u16* __restrict__ A,
                                          const u16* __restrict__ W,
                                          u16* As, u16* Bs,
                                          f32x4 (&acc)[4][4],
                                          int m0, int n0, int K) {
  int tid = threadIdx.x;
  int lane = tid & 63, wid = tid >> 6;
  int wr = wid >> 1, wc = wid & 1;

  int arow = wid * 16 + (lane >> 2);
  int ag = lane & 3;
  int sg = ag ^ ((arow >> 1) & 3);
  const u16* aSrc0 = A + (size_t)(m0 + arow) * K + sg * 8;
  const u16* aSrc1 = aSrc0 + (size_t)64 * K;
  const u16* bSrc0 = W + (size_t)(n0 + arow) * K + sg * 8;
  const u16* bSrc1 = bSrc0 + (size_t)64 * K;
  u16* aDst0 = As + (wid * 16) * 32;
  u16* aDst1 = As + (64 + wid * 16) * 32;
  u16* bDst0 = Bs + (wid * 16) * 32;
  u16* bDst1 = Bs + (64 + wid * 16) * 32;

  int rg = lane >> 4;
  int aoff[4], boff[4];
#pragma unroll
  for (int m = 0; m < 4; ++m) {
    int row = wr * 64 + m * 16 + (lane & 15);
    aoff[m] = row * 32 + (rg ^ ((row >> 1) & 3)) * 8;
    row = wc * 64 + m * 16 + (lane & 15);
    boff[m] = row * 32 + (rg ^ ((row >> 1) & 3)) * 8;
  }

  for (int kt = 0; kt < K / 32; ++kt) {
    int k0 = kt * 32;
    __syncthreads();
    gload16(aSrc0 + k0, aDst0);
    gload16(aSrc1 + k0, aDst1);
    gload16(bSrc0 + k0, bDst0);
    gload16(bSrc1 + k0, bDst1);
    __syncthreads();

    bf16x8 af[4], bfr[4];
#pragma unroll
    for (int m = 0; m < 4; ++m) af[m] = *(const bf16x8*)(As + aoff[m]);
#pragma unroll
    for (int n = 0; n < 4; ++n) bfr[n] = *(const bf16x8*)(Bs + boff[n]);
#pragma unroll
    for (int m = 0; m < 4; ++m)
#pragma unroll
      for (int n = 0; n < 4; ++n)
        acc[m][n] = __builtin_amdgcn_mfma_f32_16x16x32_bf16(af[m], bfr[n], acc[m][n], 0, 0, 0);
  }
}

// ---------------- GEMM1 (R19 exact): qkv = x @ W_attn^T + b; Q pre-scaled ----------------
__global__ __launch_bounds__(256) void gemm_qkv(const u16* __restrict__ A,
                                                const u16* __restrict__ W,
                                                const float* __restrict__ bias,
                                                u16* __restrict__ Qb,
                                                u16* __restrict__ Kb,
                                                u16* __restrict__ Vt) {
  __shared__ __align__(16) u16 As[128 * 32];
  __shared__ __align__(16) u16 Bs[128 * 32];
  f32x4 acc[4][4] = {};
  int m0 = blockIdx.x * 128, n0 = blockIdx.y * 128;
  gemm_core(A, W, As, Bs, acc, m0, n0, C_);

  int lane = threadIdx.x & 63, wid = threadIdx.x >> 6;
  int wr = wid >> 1, wc = wid & 1;
  int rg = lane >> 4, cl = lane & 15;
#pragma unroll
  for (int n = 0; n < 4; ++n) {
    int gn = n0 + wc * 64 + n * 16 + cl;
    float bv = bias[gn];
    int seg = gn >> 10, cc = gn & 1023;
    int h = cc >> 6, d = cc & 63;
    float sc = (seg == 0) ? QSCALE : 1.0f;
#pragma unroll
    for (int m = 0; m < 4; ++m) {
#pragma unroll
      for (int r = 0; r < 4; ++r) {
        int gm = m0 + wr * 64 + m * 16 + rg * 4 + r;
        int b = gm >> 11, t = gm & 2047;
        u16 val = f2bf((acc[m][n][r] + bv) * sc);
        int bh = b * 16 + h;
        if (seg == 0)      Qb[((size_t)(bh * 2048 + t)) * 64 + d] = val;
        else if (seg == 1) Kb[((size_t)(bh * 2048 + t)) * 64 + d] = val;
        else               Vt[((size_t)(bh * 64 + d)) * 2048 + t] = val;
      }
    }
  }
}

// ---------------- GEMM2: out = y @ W_proj^T + b (fp32 out) ----------------
__global__ __launch_bounds__(256) void gemm_proj(const u16* __restrict__ A,
                                                 const u16* __restrict__ W,
                                                 const float* __restrict__ bias,
                                                 float* __restrict__ out) {
  __shared__ __align__(16) u16 As[128 * 32];
  __shared__ __align__(16) u16 Bs[128 * 32];
  f32x4 acc[4][4] = {};
  int m0 = blockIdx.x * 128, n0 = blockIdx.y * 128;
  gemm_core(A, W, As, Bs, acc, m0, n0, C_);

  int lane = threadIdx.x & 63, wid = threadIdx.x >> 6;
  int wr = wid >> 1, wc = wid & 1;
  int rg = lane >> 4, cl = lane & 15;
#pragma unroll
  for (int n = 0; n < 4; ++n) {
    int gn = n0 + wc * 64 + n * 16 + cl;
    float bv = bias[gn];
#pragma unroll
    for (int m = 0; m < 4; ++m) {
#pragma unroll
      for (int r = 0; r < 4; ++r) {
        int gm = m0 + wr * 64 + m * 16 + rg * 4 + r;
        out[(size_t)gm * 1024 + gn] = acc[m][n][r] + bv;
      }
    }
  }
}

// ---------------- flash attention v20: 8-wave shared staging + kv-split ----------------
// Block = (bh, qt): 128 q-rows, 512 threads. Wave (w4,kvh) = 32 q-rows x
// 32 kv-cols of every tile: R19's shared K/V staging (/8 VMEM, 1 gload16
// per wave per tile per operand) x R11's kv-split (work-neutral 2x waves:
// 16 waves/CU = 4/SIMD). No-max softmax => kvh partials add exactly; one
// LDS combine at the epilogue (aliased onto dead Ks/Vs).
__global__ __launch_bounds__(512, 2) void attn_fwd(const u16* __restrict__ Qb,
                                                   const u16* __restrict__ Kb,
                                                   const u16* __restrict__ Vt,
                                                   u16* __restrict__ Yb) {
  __shared__ __align__(16) u16 Ks[2][64 * 64];   // [buf][kv][d] swizzled (16KB)
  __shared__ __align__(16) u16 Vs[2][64 * 64];   // [buf][d][kv] swizzled (16KB)
  __shared__ __align__(16) u16 Ps[8][32 * 32];   // per-wave P (16KB)
  int tid = threadIdx.x, lane = tid & 63, w = tid >> 6;   // w in 0..7
  int w4 = w >> 1, kvh = w & 1;
  int cl = lane & 15, kg = lane >> 4;
  int sw = (cl ^ (cl >> 2)) & 3;        // P-tile granule swizzle
  int bid = blockIdx.x;
  int bh = bid & 31;                    // CU-local head
  int i = bid >> 5;
  int qt = (i < 8) ? i : 23 - i;        // per-CU pair (x,15-x): equal work
  int qb0 = qt * 128 + w4 * 32;         // this wave's first q row
  int jmaxw = (qb0 + 31) >> 6;          // wave's diagonal tile
  int jmaxb = 2 * qt + 1;               // block's last tile
  bool hasHigh = (qb0 & 32) != 0;       // diagonal tile's upper kv half live
  const u16* Qp = Qb + (size_t)bh * (2048 * 64);
  const u16* Kp = Kb + (size_t)bh * (2048 * 64);
  const u16* Vp = Vt + (size_t)bh * (64 * 2048);
  u16* Pw = Ps[w];

  // staging: wave w stages rows [8w,8w+8) of K and of V (pre-swizzled src)
  int srow8 = lane >> 3;
  int sg = (lane & 7) ^ srow8;
  const u16* Ksrc = Kp + (w * 8 + srow8) * 64 + sg * 8;
  const u16* Vsrc = Vp + (w * 8 + srow8) * 2048 + sg * 8;

  // Q fragments (B-operand): q = qb0 + fr*16 + cl, d-slice dk*32 + kg*8
  bf16x8 qf[2][2];
#pragma unroll
  for (int fr = 0; fr < 2; ++fr)
#pragma unroll
    for (int dk = 0; dk < 2; ++dk)
      qf[fr][dk] = *(const bf16x8*)(Qp + (qb0 + fr * 16 + cl) * 64 + dk * 32 + kg * 8);

  f32x4 o[2][4] = {};
  float lsum[2] = {0.f, 0.f};
  const f32x4 CINIT = {-C8, -C8, -C8, -C8};

  auto STAGE = [&](int j, int buf) {
    gload16(Ksrc + j * 4096, &Ks[buf][w * 512]);
    gload16(Vsrc + j * 64, &Vs[buf][w * 512]);
  };

  auto CORE = [&](int buf, int j, bool mask) {
    const u16* Kl = Ks[buf];
    const u16* Vl = Vs[buf];
    // K frags: kv rows (kvh*2+fcl)*16+cl, d granules dk*4+kg
    bf16x8 kf[2][2];
#pragma unroll
    for (int fcl = 0; fcl < 2; ++fcl) {
      int row = (kvh * 2 + fcl) * 16 + cl;
      kf[fcl][0] = *(const bf16x8*)(Kl + row * 64 + ((kg ^ (cl & 7)) * 8));
      kf[fcl][1] = *(const bf16x8*)(Kl + row * 64 + (((4 + kg) ^ (cl & 7)) * 8));
    }
    // V frags: d rows dc*16+cl, own kv half granules kvh*4+kg
    bf16x8 vf[4];
#pragma unroll
    for (int dc = 0; dc < 4; ++dc) {
      int row = dc * 16 + cl;
      vf[dc] = *(const bf16x8*)(Vl + row * 64 + (((kvh * 4 + kg) ^ (cl & 7)) * 8));
    }
    // S^T = K Q^T - C8 : lane holds q = fr*16+cl, kv = (kvh*2+fcl)*16+kg*4+r
    f32x4 s[2][2];
#pragma unroll
    for (int fcl = 0; fcl < 2; ++fcl)
#pragma unroll
      for (int fr = 0; fr < 2; ++fr) {
        f32x4 z = CINIT;
        z = __builtin_amdgcn_mfma_f32_16x16x32_bf16(kf[fcl][0], qf[fr][0], z, 0, 0, 0);
        z = __builtin_amdgcn_mfma_f32_16x16x32_bf16(kf[fcl][1], qf[fr][1], z, 0, 0, 0);
        s[fr][fcl] = z;
      }
    if (mask) {
#pragma unroll
      for (int fr = 0; fr < 2; ++fr) {
        int qg = qb0 + fr * 16 + cl;
#pragma unroll
        for (int fcl = 0; fcl < 2; ++fcl)
#pragma unroll
          for (int r = 0; r < 4; ++r)
            if (j * 64 + (kvh * 2 + fcl) * 16 + kg * 4 + r > qg) s[fr][fcl][r] = -1e30f;
      }
    }
    // P = exp2(S); lsum; write P (32-wide per-wave tile, sw-swizzled)
#pragma unroll
    for (int fr = 0; fr < 2; ++fr) {
      int rowb = (fr * 16 + cl) * 32;
#pragma unroll
      for (int fcl = 0; fcl < 2; ++fcl) {
        float p0 = exp2f(s[fr][fcl][0]);
        float p1 = exp2f(s[fr][fcl][1]);
        float p2 = exp2f(s[fr][fcl][2]);
        float p3 = exp2f(s[fr][fcl][3]);
        lsum[fr] += (p0 + p1) + (p2 + p3);
        union { bf16x4 v; __hip_bfloat162 h[2]; } pk;
        pk.h[0] = __float22bfloat162_rn(make_float2(p0, p1));
        pk.h[1] = __float22bfloat162_rn(make_float2(p2, p3));
        *(bf16x4*)(Pw + rowb + (((fcl * 2 + (kg >> 1)) ^ sw) * 8) + (kg & 1) * 4) = pk.v;
      }
    }
    // P A-frag (K=32 over own kv half) + PV
    bf16x8 pf[2];
#pragma unroll
    for (int fr = 0; fr < 2; ++fr)
      pf[fr] = *(const bf16x8*)(Pw + (fr * 16 + cl) * 32 + ((kg ^ sw) * 8));
#pragma unroll
    for (int fr = 0; fr < 2; ++fr)
#pragma unroll
      for (int dc = 0; dc < 4; ++dc)
        o[fr][dc] = __builtin_amdgcn_mfma_f32_16x16x32_bf16(pf[fr], vf[dc], o[fr][dc], 0, 0, 0);
  };

  STAGE(0, 0);
  __syncthreads();
  int buf = 0;
  for (int j = 0; j <= jmaxb; ++j) {
    if (j < jmaxb) STAGE(j + 1, buf ^ 1);
    if (j < jmaxw)       CORE(buf, j, false);
    else if (j == jmaxw && (kvh == 0 || hasHigh)) CORE(buf, j, true);
    __syncthreads();                    // stage drained + all waves done with buf
    buf ^= 1;
  }

  // combine kvh pairs via LDS aliased onto dead Ks/Vs; Cl onto Ps
  f32x4* Co = (f32x4*)((w4 < 2) ? (void*)&Ks[0][0] : (void*)&Vs[0][0]) + (w4 & 1) * 512;
  float*  Cl = (float*)&Ps[0][0] + w4 * 128;
  if (kvh == 1) {
#pragma unroll
    for (int fr = 0; fr < 2; ++fr) {
      Cl[fr * 64 + lane] = lsum[fr];
#pragma unroll
      for (int dc = 0; dc < 4; ++dc) Co[(fr * 4 + dc) * 64 + lane] = o[fr][dc];
    }
  }
  __syncthreads();
  if (kvh == 0) {
    int b = bh >> 4, h = bh & 15;
#pragma unroll
    for (int fr = 0; fr < 2; ++fr) {
      float l = lsum[fr] + Cl[fr * 64 + lane];
#pragma unroll
      for (int dc = 0; dc < 4; ++dc) o[fr][dc] += Co[(fr * 4 + dc) * 64 + lane];
      l += __shfl_xor(l, 16);
      l += __shfl_xor(l, 32);
      float linv = 1.f / l;
      float li[4];
#pragma unroll
      for (int r = 0; r < 4; ++r) li[r] = __shfl(linv, kg * 4 + r);
#pragma unroll
      for (int dc = 0; dc < 4; ++dc)
#pragma unroll
        for (int r = 0; r < 4; ++r) {
          int t = qb0 + fr * 16 + kg * 4 + r;
          int d = dc * 16 + cl;
          Yb[((size_t)(b * 2048 + t)) * 1024 + h * 64 + d] = f2bf(o[fr][dc][r] * li[r]);
        }
    }
  }
}

extern "C" void kernel_launch(void* const* d_in, const int* in_sizes, int n_in,
                              void* d_out, int out_size, void* d_ws, size_t ws_size,
                              hipStream_t stream) {
  const float* x  = (const float*)d_in[0];
  const float* Wa = (const float*)d_in[1];
  const float* ba = (const float*)d_in[2];
  const float* Wp = (const float*)d_in[3];
  const float* bp = (const float*)d_in[4];
  float* out = (float*)d_out;

  u16* xb  = (u16*)d_ws;
  u16* Wab = xb  + (size_t)M_ * C_;
  u16* Wpb = Wab + (size_t)N1_ * C_;
  u16* Qb  = Wpb + (size_t)C_ * C_;
  u16* Kb  = Qb  + (size_t)M_ * C_;
  u16* Vt  = Kb  + (size_t)M_ * C_;
  u16* Yb  = Vt  + (size_t)M_ * C_;

  cvt3<<<(M_ * C_ + N1_ * C_ + C_ * C_) / 2048, 256, 0, stream>>>(x, Wa, Wp, xb);
  gemm_qkv<<<dim3(M_ / 128, N1_ / 128), 256, 0, stream>>>(xb, Wab, ba, Qb, Kb, Vt);
  attn_fwd<<<512, 512, 0, stream>>>(Qb, Kb, Vt, Yb);
  gemm_proj<<<dim3(M_ / 128, C_ / 128), 256, 0, stream>>>(Yb, Wpb, bp, out);
}